// Round 9
// baseline (737.447 us; speedup 1.0000x reference)
//
#include <hip/hip_runtime.h>
#include <hip/hip_bf16.h>

#define BATCH 8192
#define SDIM  256
#define HID   128
#define LAT   64
#define NCODE 16384

// One fused kernel: block = 32 rows, 256 threads, scans all 16384 codes.
// No workspace, no inter-kernel dependencies, no cross-block communication.
// OUTPUT IS FLOAT32 (reference output dtype): z_q [8192*64] f32, then indices [8192] f32.
__global__ __launch_bounds__(256, 1) void kfused_kernel(
    const float* __restrict__ x, const float* __restrict__ W1, const float* __restrict__ b1,
    const float* __restrict__ W2, const float* __restrict__ b2, const float* __restrict__ cb,
    float* __restrict__ out)
{
  // regionA: max(xs 2176 + w1t 8448, w2 8704, cs 8704) = 10624 floats
  // regionB: max(hs 4224, zes 2176) = 4224 floats        total 59392 B
  __shared__ float regionA[10624];
  __shared__ float regionB[4224];
  float* xs  = regionA;          // [32][68]   phase A
  float* w1t = regionA + 2176;   // [64 k][132 c] phase A
  float* w2  = regionA;          // [128 k][68 c] phase B
  float* cs  = regionA;          // [128 code][68 k] dist phase
  float* hs  = regionB;          // [32][132]
  float* zes = regionB;          // [32][68] (overwrites hs after sync)

  const int tid  = threadIdx.x;
  const int tx16 = tid & 15, ty16 = tid >> 4;   // encoder mapping
  const int tx32 = tid & 31, ty8  = tid >> 5;   // distance mapping
  const int rowBase = blockIdx.x * 32;

  const float4* x4  = reinterpret_cast<const float4*>(x);
  const float4* W14 = reinterpret_cast<const float4*>(W1);
  const float4* W24 = reinterpret_cast<const float4*>(W2);
  const float4* cb4 = reinterpret_cast<const float4*>(cb);

  // ---------- phase A: h = relu(x @ W1 + b1), K=256 in 4 tiles of 64 ----------
  float acc[2][8];
#pragma unroll
  for (int i = 0; i < 2; ++i)
#pragma unroll
    for (int j = 0; j < 8; ++j) acc[i][j] = 0.f;

  for (int kt = 0; kt < 4; ++kt) {
    // stage x sub-tile [32 rows][64 k] -> xs[row*68 + k]
#pragma unroll
    for (int i = 0; i < 2; ++i) {
      int f4i = i * 256 + tid;
      int row = f4i >> 4, k4 = f4i & 15;
      *reinterpret_cast<float4*>(&xs[row * 68 + k4 * 4]) =
          x4[(rowBase + row) * 64 + kt * 16 + k4];
    }
    // stage W1 sub-tile [64 k][128 c] natural row-major -> w1t[k*132 + c]
#pragma unroll
    for (int i = 0; i < 8; ++i) {
      int f4i = i * 256 + tid;
      int k = f4i >> 5, c4 = f4i & 31;
      *reinterpret_cast<float4*>(&w1t[k * 132 + c4 * 4]) =
          W14[(kt * 64 + k) * 32 + c4];
    }
    __syncthreads();
#pragma unroll 8
    for (int kk = 0; kk < 64; ++kk) {
      float a0 = xs[(ty16 * 2 + 0) * 68 + kk];
      float a1 = xs[(ty16 * 2 + 1) * 68 + kk];
      float4 bv0 = *reinterpret_cast<const float4*>(&w1t[kk * 132 + tx16 * 8]);
      float4 bv1 = *reinterpret_cast<const float4*>(&w1t[kk * 132 + tx16 * 8 + 4]);
      acc[0][0] = fmaf(a0, bv0.x, acc[0][0]); acc[0][1] = fmaf(a0, bv0.y, acc[0][1]);
      acc[0][2] = fmaf(a0, bv0.z, acc[0][2]); acc[0][3] = fmaf(a0, bv0.w, acc[0][3]);
      acc[0][4] = fmaf(a0, bv1.x, acc[0][4]); acc[0][5] = fmaf(a0, bv1.y, acc[0][5]);
      acc[0][6] = fmaf(a0, bv1.z, acc[0][6]); acc[0][7] = fmaf(a0, bv1.w, acc[0][7]);
      acc[1][0] = fmaf(a1, bv0.x, acc[1][0]); acc[1][1] = fmaf(a1, bv0.y, acc[1][1]);
      acc[1][2] = fmaf(a1, bv0.z, acc[1][2]); acc[1][3] = fmaf(a1, bv0.w, acc[1][3]);
      acc[1][4] = fmaf(a1, bv1.x, acc[1][4]); acc[1][5] = fmaf(a1, bv1.y, acc[1][5]);
      acc[1][6] = fmaf(a1, bv1.z, acc[1][6]); acc[1][7] = fmaf(a1, bv1.w, acc[1][7]);
    }
    __syncthreads();   // xs/w1t free for restaging
  }

  // h -> hs ; then stage W2 (regionA is free after the loop's last sync)
#pragma unroll
  for (int j = 0; j < 8; ++j) {
    float bb = b1[tx16 * 8 + j];
#pragma unroll
    for (int i = 0; i < 2; ++i)
      hs[(ty16 * 2 + i) * 132 + tx16 * 8 + j] = fmaxf(acc[i][j] + bb, 0.f);
  }
#pragma unroll
  for (int i = 0; i < 8; ++i) {
    int f4i = i * 256 + tid;
    int k = f4i >> 4, c4 = f4i & 15;
    *reinterpret_cast<float4*>(&w2[k * 68 + c4 * 4]) = W24[k * 16 + c4];
  }
  __syncthreads();

  // ---------- phase B: z_e = h @ W2 + b2 ----------
  float acc2[2][4];
#pragma unroll
  for (int i = 0; i < 2; ++i)
#pragma unroll
    for (int j = 0; j < 4; ++j) acc2[i][j] = 0.f;
#pragma unroll 8
  for (int kk = 0; kk < 128; ++kk) {
    float a0 = hs[(ty16 * 2 + 0) * 132 + kk];
    float a1 = hs[(ty16 * 2 + 1) * 132 + kk];
    float4 bv = *reinterpret_cast<const float4*>(&w2[kk * 68 + tx16 * 4]);
    acc2[0][0] = fmaf(a0, bv.x, acc2[0][0]); acc2[0][1] = fmaf(a0, bv.y, acc2[0][1]);
    acc2[0][2] = fmaf(a0, bv.z, acc2[0][2]); acc2[0][3] = fmaf(a0, bv.w, acc2[0][3]);
    acc2[1][0] = fmaf(a1, bv.x, acc2[1][0]); acc2[1][1] = fmaf(a1, bv.y, acc2[1][1]);
    acc2[1][2] = fmaf(a1, bv.z, acc2[1][2]); acc2[1][3] = fmaf(a1, bv.w, acc2[1][3]);
  }
  float zef[2][4];
#pragma unroll
  for (int j = 0; j < 4; ++j) {
    float bb = b2[tx16 * 4 + j];
#pragma unroll
    for (int i = 0; i < 2; ++i) zef[i][j] = acc2[i][j] + bb;
  }
  __syncthreads();   // all hs/w2 reads complete before zes overwrites hs
#pragma unroll
  for (int i = 0; i < 2; ++i) {
    float4 v = make_float4(zef[i][0], zef[i][1], zef[i][2], zef[i][3]);
    *reinterpret_cast<float4*>(&zes[(ty16 * 2 + i) * 68 + tx16 * 4]) = v;
  }
  __syncthreads();   // zes visible to all

  // ---------- load z rows into registers (dist mapping: 4 rows/thread) ----------
  float4 zreg[4][16];
#pragma unroll
  for (int i = 0; i < 4; ++i)
#pragma unroll
    for (int q = 0; q < 16; ++q)
      zreg[i][q] = *reinterpret_cast<const float4*>(&zes[(ty8 * 4 + i) * 68 + q * 4]);

  float zns[4];
#pragma unroll
  for (int i = 0; i < 4; ++i) {
    float s = 0.f;
#pragma unroll
    for (int q = 0; q < 16; ++q) {
      float4 v = zreg[i][q];
      s = fmaf(v.x, v.x, s); s = fmaf(v.y, v.y, s);
      s = fmaf(v.z, v.z, s); s = fmaf(v.w, v.w, s);
    }
    zns[i] = s;
  }

  // ---------- distance scan: 128 tiles x 128 codes ----------
  float best[4]; int bidx[4];
#pragma unroll
  for (int i = 0; i < 4; ++i) { best[i] = 3.4e38f; bidx[i] = 0; }

  for (int t = 0; t < NCODE / 128; ++t) {
    const int c0 = t * 128;
    __syncthreads();   // previous tile's cs readers done (t=0: phase-B readers done)
#pragma unroll
    for (int i = 0; i < 8; ++i) {
      int f4i = i * 256 + tid;
      int code = f4i >> 4, k4 = f4i & 15;
      *reinterpret_cast<float4*>(&cs[code * 68 + k4 * 4]) = cb4[(c0 + code) * 16 + k4];
    }
    __syncthreads();

    float dot[4][4], cc[4];
#pragma unroll
    for (int j = 0; j < 4; ++j) {
      cc[j] = 0.f;
#pragma unroll
      for (int i = 0; i < 4; ++i) dot[i][j] = 0.f;
    }
#pragma unroll
    for (int kk = 0; kk < 16; ++kk) {
#pragma unroll
      for (int j = 0; j < 4; ++j) {
        float4 b = *reinterpret_cast<const float4*>(&cs[(tx32 + 32 * j) * 68 + kk * 4]);
        cc[j] = fmaf(b.x, b.x, cc[j]); cc[j] = fmaf(b.y, b.y, cc[j]);
        cc[j] = fmaf(b.z, b.z, cc[j]); cc[j] = fmaf(b.w, b.w, cc[j]);
#pragma unroll
        for (int i = 0; i < 4; ++i) {
          float4 a = zreg[i][kk];
          dot[i][j] = fmaf(a.x, b.x, dot[i][j]);
          dot[i][j] = fmaf(a.y, b.y, dot[i][j]);
          dot[i][j] = fmaf(a.z, b.z, dot[i][j]);
          dot[i][j] = fmaf(a.w, b.w, dot[i][j]);
        }
      }
    }
#pragma unroll
    for (int j = 0; j < 4; ++j) {
      int code = c0 + tx32 + 32 * j;
#pragma unroll
      for (int i = 0; i < 4; ++i) {
        float s = (zns[i] - 2.f * dot[i][j]) + cc[j];   // np order: (zz-2dot)+cc
        if (s < best[i]) { best[i] = s; bidx[i] = code; }  // strict <: first occurrence
      }
    }
  }

  // ---------- argmin reduce over the 32 tx lanes, then gather + store (f32!) ----------
#pragma unroll
  for (int i = 0; i < 4; ++i) {
    float b_ = best[i]; int x_ = bidx[i];
#pragma unroll
    for (int m = 1; m < 32; m <<= 1) {
      float ob = __shfl_xor(b_, m);
      int   oi = __shfl_xor(x_, m);
      if (ob < b_ || (ob == b_ && oi < x_)) { b_ = ob; x_ = oi; }
    }
    if (tx32 == 0) {
      int bi = x_ & (NCODE - 1);          // defensive clamp
      int row = rowBase + ty8 * 4 + i;
#pragma unroll
      for (int q = 0; q < 16; ++q) {
        float4 c = cb4[bi * 16 + q];
        float4 z = zreg[i][q];
        // straight-through: z_q = z_e + (z_q_raw - z_e), ref FP order
        float4 r;
        r.x = z.x + (c.x - z.x);
        r.y = z.y + (c.y - z.y);
        r.z = z.z + (c.z - z.z);
        r.w = z.w + (c.w - z.w);
        *reinterpret_cast<float4*>(&out[row * 64 + q * 4]) = r;
      }
      out[BATCH * LAT + row] = (float)bi;
    }
  }
}

extern "C" void kernel_launch(void* const* d_in, const int* in_sizes, int n_in,
                              void* d_out, int out_size, void* d_ws, size_t ws_size,
                              hipStream_t stream)
{
  // Resolve inputs BY SIZE (all six are distinct); fall back to positional.
  const float *x = (const float*)d_in[0], *W1 = (const float*)d_in[1],
              *b1 = (const float*)d_in[2], *W2 = (const float*)d_in[3],
              *b2 = (const float*)d_in[4], *cb = (const float*)d_in[5];
  for (int i = 0; i < n_in; ++i) {
    const float* p = (const float*)d_in[i];
    switch (in_sizes[i]) {
      case BATCH * SDIM:  x  = p; break;   // 2097152
      case SDIM * HID:    W1 = p; break;   // 32768
      case HID:           b1 = p; break;   // 128
      case HID * LAT:     W2 = p; break;   // 8192
      case LAT:           b2 = p; break;   // 64
      case NCODE * LAT:   cb = p; break;   // 1048576
      default: break;
    }
  }
  float* out = (float*)d_out;  // f32: z_q [8192*64] then indices [8192]

  hipLaunchKernelGGL(kfused_kernel, dim3(BATCH / 32), dim3(256), 0, stream,
                     x, W1, b1, W2, b2, cb, out);
}